// Round 13
// baseline (753.550 us; speedup 1.0000x reference)
//
#include <hip/hip_runtime.h>

namespace {

constexpr int T_LEN = 2048;
constexpr int B_TOT = 2048;
constexpr int H1 = 36;
constexpr int NB = 16;      // batches per block = MFMA N
constexpr int BLOCK = 640;  // 9 A-waves + 1 L2-MFMA/x-feeder wave
constexpr int RS = 72;      // row stride in halves (144B, 16B-aligned)

typedef _Float16 f16x8 __attribute__((ext_vector_type(8)));
typedef _Float16 h16x2 __attribute__((ext_vector_type(2)));
typedef float f32x4 __attribute__((ext_vector_type(4)));

__device__ __forceinline__ float fexp2(float x) { return __builtin_amdgcn_exp2f(x); }
__device__ __forceinline__ float frcp(float x) { return __builtin_amdgcn_rcpf(x); }

// Unit-at-k permutation: LDS half k holds unit U(k) = 4*(k%9) + k/9; unit u
// lives at k(u) = 9*(u%4) + u/4. Purpose: wave wid's 4 writes (units 4wid+q)
// land at halves {wid, 9+wid, 18+wid, 27+wid} — 4 DISTINCT spread dwords
// (old layout: q=0,1 and q=2,3 wrote halves of the same dword; 9 waves x 2
// planes of same-dword subword writes = the measured 87 conflict-cy/round).
// Readers compensate purely at setup (gather W columns by U(k)) — zero
// per-round cost. k=36..39 (x_hi, x_lo, bias, bias) unchanged.
__device__ __forceinline__ int unit_at_k(int k) { return 4 * (k % 9) + k / 9; }

// Scaled-gate LSTM cell, 8-trans form (R8-verified): pre-activations arrive
// pre-multiplied by -log2e (i,f,o) / -2log2e (g); cS tracks -2log2e*c.
__device__ __forceinline__ float lstm_unit(float pi, float pf, float pg, float po,
                                           float& cS) {
  const float Ei = fexp2(pi);
  const float Ef = fexp2(pf);
  const float Eg = fexp2(pg);
  const float Eo = fexp2(po);
  const float F = frcp(1.f + Ef);
  const float Rig = frcp((1.f + Ei) * (1.f + Eg));
  const float numg = fmaf(Eg, 2.88539008f, -2.88539008f);  // -2log2e*(1-Eg)
  cS = fmaf(F, cS, numg * Rig);
  const float Ec = fexp2(cS);
  const float Roc = frcp((1.f + Eo) * (1.f + Ec));
  return (1.f - Ec) * Roc;  // O * tanh(c)
}

// Raw barrier: producer-side lgkmcnt(0) only (no vmcnt/expcnt drain).
__device__ __forceinline__ void step_sync() {
  asm volatile("s_waitcnt lgkmcnt(0)" ::: "memory");
  __builtin_amdgcn_s_barrier();
  asm volatile("" ::: "memory");
}

__global__ __launch_bounds__(BLOCK) void lstm2_kernel(
    const float* __restrict__ x, const float* __restrict__ Wih1,
    const float* __restrict__ Whh1, const float* __restrict__ bih1,
    const float* __restrict__ bhh1, const float* __restrict__ Wih2,
    const float* __restrict__ Whh2, const float* __restrict__ bih2,
    const float* __restrict__ bhh2, float* __restrict__ out)
{
  // lds[buf][plane][batch][k]:
  //  plane0 (raw):  k=0..35 h (PERMUTED: half k holds unit U(k)),
  //                 36 x_hi, 37 x_lo, 38,39 = 1.0 (bias), 40.. = 0
  //  plane1 (relu): k=0..35 relu(h) permuted, 36,37 = 0, 38,39 = 1.0, 40.. = 0
  __shared__ __align__(16) _Float16 lds[2][2][NB][RS];

  const int tid = threadIdx.x;
  const int wid = tid >> 6;
  const int lane = tid & 63;
  const int m = lane & 15;   // A-row / B,C: batch col
  const int q = lane >> 4;   // k-group / C row-group
  const int g0 = blockIdx.x * NB;
  const bool isA = wid < 9;

  for (int i = tid; i < 2 * 2 * NB * RS; i += BLOCK)
    ((_Float16*)lds)[i] = (_Float16)0.f;
  __syncthreads();
  if (tid < NB) {  // bias columns (both bufs, both planes) + x_0 into buf1
    lds[0][0][tid][38] = (_Float16)1.f; lds[0][0][tid][39] = (_Float16)1.f;
    lds[1][0][tid][38] = (_Float16)1.f; lds[1][0][tid][39] = (_Float16)1.f;
    lds[0][1][tid][38] = (_Float16)1.f; lds[0][1][tid][39] = (_Float16)1.f;
    lds[1][1][tid][38] = (_Float16)1.f; lds[1][1][tid][39] = (_Float16)1.f;
    const float x0 = x[(size_t)(g0 + tid) * T_LEN];
    const _Float16 xh0 = (_Float16)x0;
    lds[1][0][tid][36] = xh0;
    lds[1][0][tid][37] = (_Float16)(x0 - (float)xh0);
  }
  __syncthreads();

  // ---- Operand setup (A0/A1 shared by both wave kinds) ----
  f16x8 A0 = {}, A1 = {};
  float c1 = 0.f;   // A-wave cell state
  int kw = 0;       // LDS write position for this lane's unit
  if (isA) {
    // This lane computes unit 4*wid+q (C rows 4q+r = that unit, gate r);
    // its LDS write position under the permutation is 9q+wid.
    kw = 9 * q + wid;
    const float sga = ((m & 3) == 2) ? -2.88539008f : -1.44269504f;
    const int ra = (m & 3) * H1 + (4 * wid + (m >> 2));
#pragma unroll
    for (int j = 0; j < 8; ++j)
      A0[j] = (_Float16)(sga * Whh1[ra * H1 + unit_at_k(q * 8 + j)]);
    if (q == 0) {
#pragma unroll
      for (int j = 0; j < 4; ++j)
        A1[j] = (_Float16)(sga * Whh1[ra * H1 + unit_at_k(32 + j)]);
      const _Float16 wih = (_Float16)(sga * Wih1[ra]);
      A1[4] = wih;  // * x_hi (half 36)
      A1[5] = wih;  // * x_lo (half 37)
      const float bb = sga * (bih1[ra] + bhh1[ra]);
      const _Float16 bh = (_Float16)bb;
      A1[6] = bh;                           // * 1.0 (half 38)
      A1[7] = (_Float16)(bb - (float)bh);   // * 1.0 (half 39, bias residual)
    }
  } else {
    // L2-MFMA wave: A row m = gate m for m<4 (pre-scaled), rows 4..15 zero.
    // Columns gathered by the same permutation.
    if (m < 4) {
      const float s2 = (m == 2) ? -2.88539008f : -1.44269504f;
      const float* wr = Wih2 + m * H1;
#pragma unroll
      for (int j = 0; j < 8; ++j)
        A0[j] = (_Float16)(s2 * wr[unit_at_k(q * 8 + j)]);
      if (q == 0) {
#pragma unroll
        for (int j = 0; j < 4; ++j)
          A1[j] = (_Float16)(s2 * wr[unit_at_k(32 + j)]);
        // A1[4],A1[5] stay 0 (x columns absent in layer 2)
        const float bb = s2 * (bih2[m] + bhh2[m]);
        const _Float16 bh = (_Float16)bb;
        A1[6] = bh;
        A1[7] = (_Float16)(bb - (float)bh);
      }
    }
  }

  // ---- Precomputed LDS read pointers (loop-invariant).
  // B1 broadcast trick: q!=0 lanes' B1 is structurally zero -> all point at ONE
  // shared zero 16B region (same-address -> LDS broadcast, ~free service).
  const _Float16* zr = &lds[0][1][0][40];  // never written, stays zero
  const int pl = isA ? 0 : 1;              // A reads raw, L2 reads relu
  const _Float16* b0p0 = &lds[0][pl][m][q * 8];
  const _Float16* b0p1 = &lds[1][pl][m][q * 8];
  const _Float16* b1p0 = (q == 0) ? &lds[0][pl][m][32] : zr;
  const _Float16* b1p1 = (q == 0) ? &lds[1][pl][m][32] : zr;

  // ---- L2 wave extras: per-gate recurrent weights, x-feeder state ----
  float whg4[4] = {0.f, 0.f, 0.f, 0.f};
  float c2S = 0.f, h2 = 0.f;
  float* outp = nullptr;
  const float* xc = nullptr;
  float4 qx = make_float4(0.f, 0.f, 0.f, 0.f);
  if (wid == 9) {
#pragma unroll
    for (int r = 0; r < 4; ++r)
      whg4[r] = ((r == 2) ? -2.88539008f : -1.44269504f) * Whh2[r];
    outp = out + (size_t)(g0 + m) * T_LEN;
    xc = x + (size_t)(g0 + m) * T_LEN;
    if (lane < 16) qx = *(const float4*)xc;  // x[0..3]
  }

  float4 ov = make_float4(0.f, 0.f, 0.f, 0.f);
  const f32x4 z4 = {0.f, 0.f, 0.f, 0.f};

  // Round i: A-waves compute h_i from buf[ib] (h_{i-1}, x_i) and write h_i /
  // relu(h_i) into buf[wb] at permuted positions; L2 wave feeds x_{i+1} into
  // buf[wb] and computes out[i-1] from buf[ib]'s relu plane. One raw barrier
  // per round. T5: A-waves run their dependent section at priority 1.
  auto step = [&](int i, int s, float xw) {
    const int ib = (s + 1) & 1;
    const int wb = s & 1;
    if (wid == 9 && lane < 16) {  // x_{i+1} feed (slack-side work)
      const _Float16 xh = (_Float16)xw;
      h16x2 xp = {xh, (_Float16)(xw - (float)xh)};
      *(h16x2*)&lds[wb][0][lane][36] = xp;
    }
    if (isA || i > 0) {
      if (isA) __builtin_amdgcn_s_setprio(1);
      const f16x8 B0 = *(const f16x8*)(ib ? b0p1 : b0p0);
      const f16x8 B1 = *(const f16x8*)(ib ? b1p1 : b1p0);
      const f32x4 cc1 = __builtin_amdgcn_mfma_f32_16x16x32_f16(A0, B0, z4, 0, 0, 0);
      const f32x4 cc2 = __builtin_amdgcn_mfma_f32_16x16x32_f16(A1, B1, z4, 0, 0, 0);
      if (isA) {
        const float h = lstm_unit(cc1[0] + cc2[0], cc1[1] + cc2[1],
                                  cc1[2] + cc2[2], cc1[3] + cc2[3], c1);
        const _Float16 hh = (_Float16)h;
        lds[wb][0][m][kw] = hh;
        lds[wb][1][m][kw] = (hh > (_Float16)0.f) ? hh : (_Float16)0.f;
        __builtin_amdgcn_s_setprio(0);
      } else {
        // lane (q=0, m): cc[r] = s2(r)*(W2_r . relu(h_{i-1}) + b2_r); add the
        // lane-local recurrent term and activate. q!=0 lanes compute bounded
        // garbage (zero A rows) that is never read or stored.
        float pre[4];
#pragma unroll
        for (int r = 0; r < 4; ++r)
          pre[r] = fmaf(whg4[r], h2, cc1[r] + cc2[r]);
        h2 = lstm_unit(pre[0], pre[1], pre[2], pre[3], c2S);  // = out[i-1]
        if (s == 1) ov.x = h2;
        else if (s == 2) ov.y = h2;
        else if (s == 3) ov.z = h2;
        else {
          ov.w = h2;
          if (lane < 16) *(float4*)(outp + (i - 4)) = ov;  // out[i-4..i-1]
        }
      }
    }
    step_sync();
  };

  for (int i0 = 0; i0 < T_LEN; i0 += 4) {
    float4 qn = qx;
    if (wid == 9 && lane < 16) {  // prefetch next x quad (clamped at tail)
      const int tn = (i0 + 4 < T_LEN) ? (i0 + 4) : (T_LEN - 4);
      qn = *(const float4*)(xc + tn);
    }
    step(i0 + 0, 0, qx.y);  // write x[i0+1]
    step(i0 + 1, 1, qx.z);  // write x[i0+2]
    step(i0 + 2, 2, qx.w);  // write x[i0+3]
    step(i0 + 3, 3, qn.x);  // write x[i0+4]
    qx = qn;
  }
  // Final round: A computes discarded h_2048; L2 emits out[2047] and stores
  // out[2044..2047].
  step(T_LEN, 0, qx.y);
}

}  // namespace

extern "C" void kernel_launch(void* const* d_in, const int* in_sizes, int n_in,
                              void* d_out, int out_size, void* d_ws, size_t ws_size,
                              hipStream_t stream) {
  const float* x    = (const float*)d_in[0];
  const float* Wih1 = (const float*)d_in[1];
  const float* Whh1 = (const float*)d_in[2];
  const float* bih1 = (const float*)d_in[3];
  const float* bhh1 = (const float*)d_in[4];
  const float* Wih2 = (const float*)d_in[5];
  const float* Whh2 = (const float*)d_in[6];
  const float* bih2 = (const float*)d_in[7];
  const float* bhh2 = (const float*)d_in[8];
  float* out = (float*)d_out;

  dim3 grid(B_TOT / NB);  // 128 blocks x 16 batches
  dim3 block(BLOCK);      // 9 A-waves + 1 L2-MFMA/x-feeder wave
  hipLaunchKernelGGL(lstm2_kernel, grid, block, 0, stream,
                     x, Wih1, Whh1, bih1, bhh1, Wih2, Whh2, bih2, bhh2, out);
}

// Round 14
// 750.125 us; speedup vs baseline: 1.0046x; 1.0046x over previous
//
#include <hip/hip_runtime.h>

namespace {

constexpr int T_LEN = 2048;
constexpr int B_TOT = 2048;
constexpr int H1 = 36;
constexpr int NB = 16;      // batches per block = MFMA N
constexpr int BLOCK = 640;  // 9 A-waves + 1 L2-MFMA/x-feeder wave
constexpr int RS = 72;      // row stride in halves (144B, 16B-aligned)

typedef _Float16 f16x8 __attribute__((ext_vector_type(8)));
typedef _Float16 h16x2 __attribute__((ext_vector_type(2)));
typedef float f32x4 __attribute__((ext_vector_type(4)));

__device__ __forceinline__ float fexp2(float x) { return __builtin_amdgcn_exp2f(x); }
__device__ __forceinline__ float frcp(float x) { return __builtin_amdgcn_rcpf(x); }

// Scaled-gate LSTM cell, 8-trans form (R8-verified): pre-activations arrive
// pre-multiplied by -log2e (i,f,o) / -2log2e (g); cS tracks -2log2e*c.
__device__ __forceinline__ float lstm_unit(float pi, float pf, float pg, float po,
                                           float& cS) {
  const float Ei = fexp2(pi);
  const float Ef = fexp2(pf);
  const float Eg = fexp2(pg);
  const float Eo = fexp2(po);
  const float F = frcp(1.f + Ef);
  const float Rig = frcp((1.f + Ei) * (1.f + Eg));
  const float numg = fmaf(Eg, 2.88539008f, -2.88539008f);  // -2log2e*(1-Eg)
  cS = fmaf(F, cS, numg * Rig);
  const float Ec = fexp2(cS);
  const float Roc = frcp((1.f + Eo) * (1.f + Ec));
  return (1.f - Ec) * Roc;  // O * tanh(c)
}

// Raw barrier: producer-side lgkmcnt(0) only (no vmcnt/expcnt drain) — keeps
// x prefetch / out stores in flight across rounds. Memory safety carried by
// the asm memory clobbers + side-effecting s_barrier; register-only ops stay
// free to hoist into latency shadows (R12-verified null vs sched_barrier(0),
// so this is the minimal safe form).
__device__ __forceinline__ void step_sync() {
  asm volatile("s_waitcnt lgkmcnt(0)" ::: "memory");
  __builtin_amdgcn_s_barrier();
  asm volatile("" ::: "memory");
}

__global__ __launch_bounds__(BLOCK) void lstm2_kernel(
    const float* __restrict__ x, const float* __restrict__ Wih1,
    const float* __restrict__ Whh1, const float* __restrict__ bih1,
    const float* __restrict__ bhh1, const float* __restrict__ Wih2,
    const float* __restrict__ Whh2, const float* __restrict__ bih2,
    const float* __restrict__ bhh2, float* __restrict__ out)
{
  // lds[buf][plane][batch][k]:
  //  plane0 (raw):  k=0..35 h, 36 x_hi, 37 x_lo, 38,39 = 1.0 (bias), 40.. = 0
  //  plane1 (relu): k=0..35 relu(h),    36,37 = 0,  38,39 = 1.0,      40.. = 0
  __shared__ __align__(16) _Float16 lds[2][2][NB][RS];

  const int tid = threadIdx.x;
  const int wid = tid >> 6;
  const int lane = tid & 63;
  const int m = lane & 15;   // A-row / B,C: batch col
  const int q = lane >> 4;   // k-group / C row-group
  const int g0 = blockIdx.x * NB;
  const bool isA = wid < 9;

  for (int i = tid; i < 2 * 2 * NB * RS; i += BLOCK)
    ((_Float16*)lds)[i] = (_Float16)0.f;
  __syncthreads();
  if (tid < NB) {  // bias columns (both bufs, both planes) + x_0 into buf1
    lds[0][0][tid][38] = (_Float16)1.f; lds[0][0][tid][39] = (_Float16)1.f;
    lds[1][0][tid][38] = (_Float16)1.f; lds[1][0][tid][39] = (_Float16)1.f;
    lds[0][1][tid][38] = (_Float16)1.f; lds[0][1][tid][39] = (_Float16)1.f;
    lds[1][1][tid][38] = (_Float16)1.f; lds[1][1][tid][39] = (_Float16)1.f;
    const float x0 = x[(size_t)(g0 + tid) * T_LEN];
    const _Float16 xh0 = (_Float16)x0;
    lds[1][0][tid][36] = xh0;
    lds[1][0][tid][37] = (_Float16)(x0 - (float)xh0);
  }
  __syncthreads();

  // ---- Operand setup (A0/A1 shared by both wave kinds) ----
  f16x8 A0 = {}, A1 = {};
  float c1 = 0.f;   // A-wave cell state
  int ku = 0;
  if (isA) {
    const int u0 = wid * 4;
    ku = u0 + q;  // this lane's unit (C rows 4q+r = unit u0+q, gate r)
    const float sga = ((m & 3) == 2) ? -2.88539008f : -1.44269504f;
    const int ra = (m & 3) * H1 + (u0 + (m >> 2));
#pragma unroll
    for (int j = 0; j < 8; ++j)
      A0[j] = (_Float16)(sga * Whh1[ra * H1 + q * 8 + j]);  // k=q*8+j < 32
    if (q == 0) {
#pragma unroll
      for (int j = 0; j < 4; ++j)
        A1[j] = (_Float16)(sga * Whh1[ra * H1 + 32 + j]);  // tail k=32..35
      const _Float16 wih = (_Float16)(sga * Wih1[ra]);
      A1[4] = wih;  // * x_hi
      A1[5] = wih;  // * x_lo
      const float bb = sga * (bih1[ra] + bhh1[ra]);
      const _Float16 bh = (_Float16)bb;
      A1[6] = bh;                           // * 1.0
      A1[7] = (_Float16)(bb - (float)bh);   // * 1.0 (bias residual)
    }
  } else {
    // L2-MFMA wave: A row m = gate m for m<4 (pre-scaled), rows 4..15 zero.
    // Lane (q=0, m) then receives all 4 gate pre-acts for batch m in cc[0..3].
    if (m < 4) {
      const float s2 = (m == 2) ? -2.88539008f : -1.44269504f;
      const float* wr = Wih2 + m * H1;
#pragma unroll
      for (int j = 0; j < 8; ++j)
        A0[j] = (_Float16)(s2 * wr[q * 8 + j]);
      if (q == 0) {
#pragma unroll
        for (int j = 0; j < 4; ++j)
          A1[j] = (_Float16)(s2 * wr[32 + j]);  // tail k=32..35
        // A1[4],A1[5] stay 0 (x columns absent in layer 2)
        const float bb = s2 * (bih2[m] + bhh2[m]);
        const _Float16 bh = (_Float16)bb;
        A1[6] = bh;
        A1[7] = (_Float16)(bb - (float)bh);
      }
    }
  }

  // ---- Precomputed LDS read pointers (loop-invariant).
  // B1 broadcast trick: q!=0 lanes' B1 is structurally zero -> all point at ONE
  // shared zero 16B region (same-address -> LDS broadcast, ~free service).
  const _Float16* zr = &lds[0][1][0][40];  // never written, stays zero
  const int pl = isA ? 0 : 1;              // A reads raw, L2 reads relu
  const _Float16* b0p0 = &lds[0][pl][m][q * 8];
  const _Float16* b0p1 = &lds[1][pl][m][q * 8];
  const _Float16* b1p0 = (q == 0) ? &lds[0][pl][m][32] : zr;
  const _Float16* b1p1 = (q == 0) ? &lds[1][pl][m][32] : zr;

  // ---- L2 wave extras: per-gate recurrent weights, x-feeder state ----
  float whg4[4] = {0.f, 0.f, 0.f, 0.f};
  float c2S = 0.f, h2 = 0.f;
  float* outp = nullptr;
  const float* xc = nullptr;
  float4 qx = make_float4(0.f, 0.f, 0.f, 0.f);
  if (wid == 9) {
#pragma unroll
    for (int r = 0; r < 4; ++r)
      whg4[r] = ((r == 2) ? -2.88539008f : -1.44269504f) * Whh2[r];
    outp = out + (size_t)(g0 + m) * T_LEN;
    xc = x + (size_t)(g0 + m) * T_LEN;
    if (lane < 16) qx = *(const float4*)xc;  // x[0..3]
  }

  float4 ov = make_float4(0.f, 0.f, 0.f, 0.f);
  const f32x4 z4 = {0.f, 0.f, 0.f, 0.f};

  // Round i: A-waves compute h_i from buf[ib] (h_{i-1}, x_i) and write h_i /
  // relu(h_i) into buf[wb]; L2 wave feeds x_{i+1} into buf[wb] and computes
  // out[i-1] from buf[ib]'s relu plane. One raw barrier per round.
  // T5: A-waves (the round-critical chain) run their dependent section at
  // priority 1 so they win per-cycle issue arbitration on SIMDs shared with
  // the slack-laden L2 wave.
  auto step = [&](int i, int s, float xw) {
    const int ib = (s + 1) & 1;
    const int wb = s & 1;
    if (wid == 9 && lane < 16) {  // x_{i+1} feed (slack-side work)
      const _Float16 xh = (_Float16)xw;
      h16x2 xp = {xh, (_Float16)(xw - (float)xh)};
      *(h16x2*)&lds[wb][0][lane][36] = xp;
    }
    if (isA || i > 0) {
      if (isA) __builtin_amdgcn_s_setprio(1);
      const f16x8 B0 = *(const f16x8*)(ib ? b0p1 : b0p0);
      const f16x8 B1 = *(const f16x8*)(ib ? b1p1 : b1p0);
      const f32x4 cc1 = __builtin_amdgcn_mfma_f32_16x16x32_f16(A0, B0, z4, 0, 0, 0);
      const f32x4 cc2 = __builtin_amdgcn_mfma_f32_16x16x32_f16(A1, B1, z4, 0, 0, 0);
      if (isA) {
        const float h = lstm_unit(cc1[0] + cc2[0], cc1[1] + cc2[1],
                                  cc1[2] + cc2[2], cc1[3] + cc2[3], c1);
        const _Float16 hh = (_Float16)h;
        lds[wb][0][m][ku] = hh;
        lds[wb][1][m][ku] = (hh > (_Float16)0.f) ? hh : (_Float16)0.f;
        __builtin_amdgcn_s_setprio(0);
      } else {
        // lane (q=0, m): cc[r] = s2(r)*(W2_r . relu(h_{i-1}) + b2_r); add the
        // lane-local recurrent term and activate. q!=0 lanes compute bounded
        // garbage (zero A rows) that is never read or stored.
        float pre[4];
#pragma unroll
        for (int r = 0; r < 4; ++r)
          pre[r] = fmaf(whg4[r], h2, cc1[r] + cc2[r]);
        h2 = lstm_unit(pre[0], pre[1], pre[2], pre[3], c2S);  // = out[i-1]
        if (s == 1) ov.x = h2;
        else if (s == 2) ov.y = h2;
        else if (s == 3) ov.z = h2;
        else {
          ov.w = h2;
          if (lane < 16) *(float4*)(outp + (i - 4)) = ov;  // out[i-4..i-1]
        }
      }
    }
    step_sync();
  };

  for (int i0 = 0; i0 < T_LEN; i0 += 4) {
    float4 qn = qx;
    if (wid == 9 && lane < 16) {  // prefetch next x quad (clamped at tail)
      const int tn = (i0 + 4 < T_LEN) ? (i0 + 4) : (T_LEN - 4);
      qn = *(const float4*)(xc + tn);
    }
    step(i0 + 0, 0, qx.y);  // write x[i0+1]
    step(i0 + 1, 1, qx.z);  // write x[i0+2]
    step(i0 + 2, 2, qx.w);  // write x[i0+3]
    step(i0 + 3, 3, qn.x);  // write x[i0+4]
    qx = qn;
  }
  // Final round: A computes discarded h_2048; L2 emits out[2047] and stores
  // out[2044..2047].
  step(T_LEN, 0, qx.y);
}

}  // namespace

extern "C" void kernel_launch(void* const* d_in, const int* in_sizes, int n_in,
                              void* d_out, int out_size, void* d_ws, size_t ws_size,
                              hipStream_t stream) {
  const float* x    = (const float*)d_in[0];
  const float* Wih1 = (const float*)d_in[1];
  const float* Whh1 = (const float*)d_in[2];
  const float* bih1 = (const float*)d_in[3];
  const float* bhh1 = (const float*)d_in[4];
  const float* Wih2 = (const float*)d_in[5];
  const float* Whh2 = (const float*)d_in[6];
  const float* bih2 = (const float*)d_in[7];
  const float* bhh2 = (const float*)d_in[8];
  float* out = (float*)d_out;

  dim3 grid(B_TOT / NB);  // 128 blocks x 16 batches
  dim3 block(BLOCK);      // 9 A-waves + 1 L2-MFMA/x-feeder wave
  hipLaunchKernelGGL(lstm2_kernel, grid, block, 0, stream,
                     x, Wih1, Whh1, bih1, bhh1, Wih2, Whh2, bih2, bhh2, out);
}